// Round 3
// baseline (276.183 us; speedup 1.0000x reference)
//
#include <hip/hip_runtime.h>
#include <hip/hip_bf16.h>

// SwitchLinear: B=4,S=2048,D_IN=1024,D_OUT=1024,E=8
// Established contract: ALL inputs fp32, OUTPUT fp32 (out_size=8388609 floats:
// 8192x1024 dense out + aux scalar). ws >= 262400 B. Routing = argmax of fp32
// gate logits; out[t,:] = x[t]@We[top1]^T + be[top1]; aux = mean((mean_gate*E)^2).
// Value GEMM: bf16 MFMA (input-rounding error ~1e-3 << 6.4e-2 threshold).
//
// v4: gemm restructured. (1) BK=64 (16 K-steps instead of 32 -> half the
// barrier/latency exposures, 16 global loads in flight per phase);
// (2) XOR-swizzled LDS (chunk ^= row&7) on BOTH write and read -> b128
// accesses at the 8-pass bank floor (was 16-pass writes, 4.5M conflict cyc);
// (3) 1-D grid, decode m=d&63,e,n=d>>9 so the 8 n-blocks sharing the same
// 128 x-rows land on the SAME XCD (d%8 = m%8) -> x slice L2-resident.
// v3 (kept): zero-atomic routing via per-block records + 1-block scan kernel.

#define NTOK 8192
#define DIN  1024
#define DOUT 1024
#define NE   8

typedef unsigned short u16;
typedef unsigned int   u32;
typedef unsigned long long u64;
typedef short  bf16x8 __attribute__((ext_vector_type(8)));
typedef float  f32x4  __attribute__((ext_vector_type(4)));

__device__ __forceinline__ u16 f2bf(float f) {
    __hip_bfloat16 h = __float2bfloat16(f);   // RNE
    return *(u16*)&h;
}

// ws layout: [0,32) counts[8] | [256, 262400) tok_list[8][8192]
// First 32KB of tok_list region doubles as gate-record staging (512 x 64B);
// route_kernel loads all records into regs/LDS before scattering over it.

// ---------------------------------------------------------------------------
// gate: 512 blocks x 256 thr; each block 16 tokens, each wave 4 tokens.
// Per token: 8 lane-groups x 8 lanes; group g computes expert g. No atomics.
// ---------------------------------------------------------------------------
__global__ __launch_bounds__(256) void gate_kernel(
    const float* __restrict__ x, const float* __restrict__ Wg,
    const float* __restrict__ bg, u32* __restrict__ stage)
{
    __shared__ int   am_s[16];
    __shared__ float mg_s[4][NE];

    const int tid  = threadIdx.x;
    const int wave = tid >> 6;
    const int lane = tid & 63;
    const int g    = lane >> 3;
    const int sub  = lane & 7;

    const float* wr = Wg + g * DIN + 4 * sub;

    float bgl[NE];
    #pragma unroll
    for (int e = 0; e < NE; ++e) bgl[e] = bg[e];

    float mgacc = 0.f;

    #pragma unroll 1
    for (int it = 0; it < 4; ++it) {
        const int t = blockIdx.x * 16 + wave * 4 + it;
        const float* xr = x + (size_t)t * DIN + 4 * sub;

        float acc0 = 0.f, acc1 = 0.f, acc2 = 0.f, acc3 = 0.f;
        #pragma unroll
        for (int j = 0; j < 8; ++j) {
            const int k = j * 128;
            f32x4 x0 = *(const f32x4*)(xr + k);
            f32x4 w0 = *(const f32x4*)(wr + k);
            f32x4 x1 = *(const f32x4*)(xr + k + 32);
            f32x4 w1 = *(const f32x4*)(wr + k + 32);
            f32x4 x2 = *(const f32x4*)(xr + k + 64);
            f32x4 w2 = *(const f32x4*)(wr + k + 64);
            f32x4 x3 = *(const f32x4*)(xr + k + 96);
            f32x4 w3 = *(const f32x4*)(wr + k + 96);
            #pragma unroll
            for (int q = 0; q < 4; ++q) {
                acc0 = fmaf(w0[q], x0[q], acc0);
                acc1 = fmaf(w1[q], x1[q], acc1);
                acc2 = fmaf(w2[q], x2[q], acc2);
                acc3 = fmaf(w3[q], x3[q], acc3);
            }
        }
        float acc = (acc0 + acc1) + (acc2 + acc3);

        acc += __shfl_xor(acc, 1, 64);
        acc += __shfl_xor(acc, 2, 64);
        acc += __shfl_xor(acc, 4, 64);

        float logit[NE];
        #pragma unroll
        for (int e = 0; e < NE; ++e)
            logit[e] = __shfl(acc, e * 8, 64) + bgl[e];

        float m = logit[0]; int am = 0;
        #pragma unroll
        for (int e = 1; e < NE; ++e) if (logit[e] > m) { m = logit[e]; am = e; }

        float p[NE], s = 0.f;
        #pragma unroll
        for (int e = 0; e < NE; ++e) { p[e] = __expf(logit[e] - m); s += p[e]; }
        const float inv = 1.f / s;

        float psel = p[0];
        #pragma unroll
        for (int e = 1; e < NE; ++e) psel = (lane == e) ? p[e] : psel;
        if (lane < NE) mgacc += psel * inv;

        if (lane == 0) am_s[wave * 4 + it] = am;
    }

    if (lane < NE) mg_s[wave][lane] = mgacc;
    __syncthreads();

    u32* rec = stage + (size_t)blockIdx.x * 16;
    if (tid == 0) {
        u64 pack = 0;
        #pragma unroll
        for (int i = 0; i < 16; ++i) pack |= (u64)am_s[i] << (4 * i);
        *(u64*)rec = pack;
    }
    if (tid < NE) {
        float s = mg_s[0][tid] + mg_s[1][tid] + mg_s[2][tid] + mg_s[3][tid];
        rec[2 + tid] = __float_as_uint(s);
    }
}

// ---------------------------------------------------------------------------
// route: 1 block x 512 threads. Thread i owns gate-block i (16 tokens).
// Count -> per-expert exclusive scan over blocks -> scatter -> counts/aux.
// ---------------------------------------------------------------------------
__global__ __launch_bounds__(512) void route_kernel(
    const u32* __restrict__ stage, int* __restrict__ counts,
    int* __restrict__ tok_list, float* __restrict__ out)
{
    __shared__ float mgl[512][NE];
    __shared__ int   c[512][9];
    __shared__ float tot_s[NE];

    const int tid  = threadIdx.x;
    const int wave = tid >> 6;
    const int lane = tid & 63;

    const u64 pack = *(const u64*)(stage + (size_t)tid * 16);
    #pragma unroll
    for (int e = 0; e < NE; ++e)
        mgl[tid][e] = __uint_as_float(stage[tid * 16 + 2 + e]);

    #pragma unroll
    for (int e = 0; e < 9; ++e) c[tid][e] = 0;

    #pragma unroll
    for (int it = 0; it < 16; ++it) {
        int e3 = (int)((pack >> (4 * it)) & 7);
        c[tid][e3]++;
    }
    __syncthreads();

    {
        const int e = wave;
        int carry = 0;
        #pragma unroll 1
        for (int ch = 0; ch < 8; ++ch) {
            int v = c[ch * 64 + lane][e];
            int incl = v;
            #pragma unroll
            for (int off = 1; off < 64; off <<= 1) {
                int n = __shfl_up(incl, off, 64);
                if (lane >= off) incl += n;
            }
            c[ch * 64 + lane][e] = incl - v + carry;
            carry += __shfl(incl, 63, 64);
        }
        if (lane == 0) counts[e] = carry;
    }
    __syncthreads();

    #pragma unroll
    for (int it = 0; it < 16; ++it) {
        int e3 = (int)((pack >> (4 * it)) & 7);
        int pos = c[tid][e3]++;
        tok_list[e3 * NTOK + pos] = tid * 16 + it;
    }

    {
        const int e = wave;
        float s = 0.f;
        #pragma unroll
        for (int ch = 0; ch < 8; ++ch) s += mgl[ch * 64 + lane][e];
        #pragma unroll
        for (int off = 32; off > 0; off >>= 1) s += __shfl_xor(s, off, 64);
        if (lane == 0) tot_s[e] = s;
    }
    __syncthreads();
    if (tid == 0) {
        float s = 0.f;
        #pragma unroll
        for (int e = 0; e < NE; ++e) {
            float m = tot_s[e] * (8.0f / 8192.0f);
            s += m * m;
        }
        out[(size_t)NTOK * DOUT] = s * 0.125f;
    }
}

// ---------------------------------------------------------------------------
// grouped GEMM v4: per expert e, C[rows(e),1024] = X[rows(e),:] @ We[e]^T + be
// 128x128 tile, BK=64, 4 waves each 64x64 (4x4 of mfma 16x16x32, ks=0,1).
// LDS: sA/sB [128 rows][8 chunks of 8 bf16], stored chunk = c ^ (row&7)
// (XOR swizzle, write+read both at the 8-pass b128 bank floor).
// Grid: 1-D 4096; decode m=d&63, e=(d>>6)&7, n=d>>9 -> the 8 n-siblings of
// one (m,e) share d%8 -> same XCD -> shared x rows are L2-resident.
// ---------------------------------------------------------------------------
__global__ __launch_bounds__(256) void moe_gemm(
    const float* __restrict__ x, const float* __restrict__ We,
    const float* __restrict__ be, const int* __restrict__ counts,
    const int* __restrict__ tok_list, float* __restrict__ out)
{
    const int d  = blockIdx.x;
    const int e  = (d >> 6) & 7;
    const int cnt = counts[e];
    const int m0 = (d & 63) * 128;
    if (m0 >= cnt) return;
    const int n0 = (d >> 9) * 128;

    __shared__ u16 sA[128 * 64];
    __shared__ u16 sB[128 * 64];
    __shared__ int toks[128];

    const int tid = threadIdx.x;
    if (tid < 128) {
        int gr = m0 + tid;
        toks[tid] = (gr < cnt) ? tok_list[e * NTOK + gr] : tok_list[e * NTOK];
    }
    __syncthreads();

    const int lane = tid & 63;
    const int wave = tid >> 6;
    const int wm   = (wave & 1) * 64;
    const int wn   = (wave >> 1) * 64;
    const int lrow = lane & 15;
    const int quad = lane >> 4;

    f32x4 acc[4][4];
    #pragma unroll
    for (int i = 0; i < 4; ++i)
        #pragma unroll
        for (int j = 0; j < 4; ++j) acc[i][j] = (f32x4){0.f, 0.f, 0.f, 0.f};

    // staging map: thread covers rows p*32 + (tid>>3), chunk c = tid&7
    // (8 bf16 = 16B per chunk); stored chunk = c ^ (row&7).
    const int t3 = tid >> 3;
    const int ch = tid & 7;
    const int cx = ch ^ (t3 & 7);          // row&7 == (tid>>3)&7 for all p

    const float* aP[4];
    const float* bP[4];
    #pragma unroll
    for (int p = 0; p < 4; ++p) {
        const int r = p * 32 + t3;
        aP[p] = x  + (size_t)toks[r] * DIN + ch * 8;
        bP[p] = We + ((size_t)e << 20) + ((size_t)(n0 + r) << 10) + ch * 8;
    }

    // read-side swizzled chunk offsets (in elems): (slot ^ (lrow&7)) * 8
    const int l7 = lrow & 7;

    #pragma unroll 1
    for (int k0 = 0; k0 < DIN; k0 += 64) {
        f32x4 a0[4], a1[4], b0[4], b1[4];
        #pragma unroll
        for (int p = 0; p < 4; ++p) {
            a0[p] = *(const f32x4*)(aP[p] + k0);
            a1[p] = *(const f32x4*)(aP[p] + k0 + 4);
            b0[p] = *(const f32x4*)(bP[p] + k0);
            b1[p] = *(const f32x4*)(bP[p] + k0 + 4);
        }
        #pragma unroll
        for (int p = 0; p < 4; ++p) {
            union { u16 h[8]; uint4 u; } ua, ub;
            #pragma unroll
            for (int q = 0; q < 4; ++q) {
                ua.h[q]     = f2bf(a0[p][q]);
                ua.h[4 + q] = f2bf(a1[p][q]);
                ub.h[q]     = f2bf(b0[p][q]);
                ub.h[4 + q] = f2bf(b1[p][q]);
            }
            const int r = p * 32 + t3;
            *(uint4*)&sA[r * 64 + cx * 8] = ua.u;
            *(uint4*)&sB[r * 64 + cx * 8] = ub.u;
        }
        __syncthreads();

        bf16x8 af[2][4], bfr[2][4];
        #pragma unroll
        for (int ks = 0; ks < 2; ++ks) {
            const int so = ((ks * 4 + quad) ^ l7) * 8;
            #pragma unroll
            for (int i = 0; i < 4; ++i) {
                af[ks][i]  = *(const bf16x8*)&sA[(wm + i * 16 + lrow) * 64 + so];
                bfr[ks][i] = *(const bf16x8*)&sB[(wn + i * 16 + lrow) * 64 + so];
            }
        }
        #pragma unroll
        for (int ks = 0; ks < 2; ++ks)
            #pragma unroll
            for (int i = 0; i < 4; ++i)
                #pragma unroll
                for (int j = 0; j < 4; ++j)
                    acc[i][j] = __builtin_amdgcn_mfma_f32_16x16x32_bf16(
                        af[ks][i], bfr[ks][j], acc[i][j], 0, 0, 0);
        __syncthreads();
    }

    // epilogue: D lane map col=lane&15 (N), row=quad*4+r (M); fp32 stores
    #pragma unroll
    for (int j = 0; j < 4; ++j) {
        const int col = n0 + wn + j * 16 + lrow;
        const float bev = be[e * DOUT + col];
        #pragma unroll
        for (int i = 0; i < 4; ++i) {
            #pragma unroll
            for (int r = 0; r < 4; ++r) {
                const int rl = wm + i * 16 + quad * 4 + r;
                if (m0 + rl < cnt) {
                    const int tok = toks[rl];
                    out[((size_t)tok << 10) + col] = acc[i][j][r] + bev;
                }
            }
        }
    }
}

extern "C" void kernel_launch(void* const* d_in, const int* in_sizes, int n_in,
                              void* d_out, int out_size, void* d_ws, size_t ws_size,
                              hipStream_t stream) {
    const float* x  = (const float*)d_in[0];
    const float* We = (const float*)d_in[1];
    const float* be = (const float*)d_in[2];
    const float* Wg = (const float*)d_in[3];
    const float* bg = (const float*)d_in[4];
    float* out = (float*)d_out;

    int* counts   = (int*)d_ws;
    int* tok_list = (int*)((char*)d_ws + 256);
    u32* stage    = (u32*)((char*)d_ws + 256);

    gate_kernel<<<512, 256, 0, stream>>>(x, Wg, bg, stage);
    route_kernel<<<1, 512, 0, stream>>>(stage, counts, tok_list, out);
    moe_gemm<<<4096, 256, 0, stream>>>(x, We, be, counts, tok_list, out);
}